// Round 10
// baseline (106.302 us; speedup 1.0000x reference)
//
#include <hip/hip_runtime.h>
#include <hip/hip_bf16.h>

typedef unsigned short u16;
typedef __attribute__((ext_vector_type(8))) short short8;
typedef __attribute__((ext_vector_type(16))) float floatx16;

#define NROWS 8192
#define DIM 256

__device__ __forceinline__ void atomicMinFloat(float* addr, float val) {
    if (val >= 0.0f) {
        atomicMin((int*)addr, __float_as_int(val));
    } else {
        atomicMax((unsigned int*)addr, __float_as_uint(val));
    }
}

__device__ __forceinline__ u16 f32_to_bf16_rne(float x) {
    unsigned int u = __float_as_uint(x);
    unsigned int r = (u + 0x7fffu + ((u >> 16) & 1u)) >> 16;
    return (u16)r;
}

// C(M) = -logp * exp(logp); quasiconcave in M => rowmin = min(C(minM), C(maxM)).
__device__ __forceinline__ float c_of_m(float m) {
    const float INV_SIG = 1.0f / 0.3f;
    const float KC = 0.28503427f;  // -ln(0.3) - 0.5*ln(2*pi)
    float z = (m - 1.0f) * INV_SIG;
    float logp = fmaf(-0.5f * z, z, KC);
    return -logp * __expf(logp);
}

// 16B async DMA global -> LDS. LDS dest is wave-uniform base + lane*16.
__device__ __forceinline__ void load16(const u16* g, u16* l) {
    __builtin_amdgcn_global_load_lds(
        (__attribute__((address_space(1))) void*)g,
        (__attribute__((address_space(3))) void*)l, 16, 0, 0);
}

// Normalize rows (L2-norm clamped at 1e-8), wave per row, float4 loads.
// R26: panel layout for mfma_f32_32x32x16_bf16 (32-row panels, K-chunk 16):
//   element (row r, k) -> flat[ ((p32*16 + kt)*64 + half*32 + rr)*8 + j ]
//   p32=r>>5, rr=r&31, kt=k>>4, half=(k>>3)&1, j=k&7.
// Fragment (p32,kt) = 64 lanes x 16B: lane l holds row (l&31), k-chunk
// (l>>5)*8+j -- the verified 16x16x32 pattern with gfx950's family-wide
// lane-group doubling. A fragment load is base + lane*16B, one dwordx4.
__global__ __launch_bounds__(256) void normalize_kernel(const float* __restrict__ Ex,
                                                        const float* __restrict__ Ey,
                                                        u16* __restrict__ Xs,
                                                        u16* __restrict__ Ys,
                                                        float* __restrict__ out) {
    const int t = threadIdx.x;
    const int ln = t & 63;
    const int row = blockIdx.x * 4 + (t >> 6);
    const float* src = (blockIdx.y == 0) ? Ex : Ey;
    u16* dst = (blockIdx.y == 0) ? Xs : Ys;

    float4 v = *(const float4*)(src + (size_t)row * DIM + ln * 4);
    float s = fmaf(v.x, v.x, fmaf(v.y, v.y, fmaf(v.z, v.z, v.w * v.w)));
    #pragma unroll
    for (int m = 32; m >= 1; m >>= 1) s += __shfl_xor(s, m, 64);
    float inv = 1.0f / fmaxf(sqrtf(s), 1e-8f);

    ushort4 o;
    o.x = f32_to_bf16_rne(v.x * inv);
    o.y = f32_to_bf16_rne(v.y * inv);
    o.z = f32_to_bf16_rne(v.z * inv);
    o.w = f32_to_bf16_rne(v.w * inv);

    // k = ln*4 + c: kt = ln>>2, half = (ln>>1)&1, j0 = (ln&1)*4.
    const int p32 = row >> 5;
    const int rr = row & 31;
    const int kt = ln >> 2;
    const int half = (ln >> 1) & 1;
    const int j0 = (ln & 1) * 4;
    const size_t off = ((size_t)(p32 * 16 + kt) * 64 + half * 32 + rr) * 8 + j0;
    *(ushort4*)(dst + off) = o;

    if (blockIdx.y == 0 && ln == 0) out[row] = __uint_as_float(0x7f800000u);  // +inf
}

// R26: 32x32x16 MFMA port + 3-phase-deep B-ring. R7/R8/R9 established:
// gemm ~4300 cyc/ct vs walls LDS 1536 / MFMA 620 -> LDS-LATENCY-bound, and
// VGPR_Count=108 (compiler holds a[]/acc in AGPRs; registers not binding).
// Levers: (1) mfma_f32_32x32x16_bf16: +15% rate ceiling (2382 vs 2075 TF),
// HALF the MFMA issue slots, same LDS read count. Wave = 64 rows x 32 cols
// = 2 row-tiles of 32x32; acc[2] f32x16; a[2][16] (kt of K=16).
// (2) 4-slot B ring bf[(kt+3)&3] (static indices after full unroll): reads
// issue 3 phases (~150-200 cyc) ahead -- beyond loaded LDS latency.
// C/D layout (m74/m101 measured): col=lane&31, row=(reg&3)+8*(reg>>2)
// +4*(lane>>5). Early-fold retained; R9's rotation/waitcnt reverted.
// Grid 256 (1 block/CU); XCD swizzle keeps A+B in the local L2.
__global__ void __launch_bounds__(512, 2)
gemm_min_kernel(const u16* __restrict__ Xs,
                const u16* __restrict__ Ys,
                float* __restrict__ out) {
    __shared__ u16 Bs[2][16 * 512];  // 2 x 16 KB (16 kt-frags x 1 KB)

    const int tid = threadIdx.x;
    const int w = tid >> 6;      // 0..7 row-group (64 rows each)
    const int lane = tid & 63;

    // XCD-aware remap (dispatch i -> XCD i&7 round-robin): XCD x gets a
    // 4 row-tile x 8 col-group region. Bijective over the 16x16 grid.
    const int i = blockIdx.x;
    const int x = i & 7;
    const int jj = i >> 3;                      // 0..31 within XCD
    const int rt = (x & 3) * 4 + (jj & 3);      // row-tile 0..15
    const int cgrp = (x >> 2) * 8 + (jj >> 2);  // col-group 0..15

    const int rowStart = rt * 512;
    const int p32A = rt * 16 + w * 2;  // wave's 2 consecutive 32-row panels
    const u16* ybase = Ys + (size_t)cgrp * 16 * 8192;  // advances 8192 u16/ct

    // Stage one 32col x 256k B tile (16 KB = 16 kt-frags x 1 KB) via DMA.
    // 8 waves x 2 units; unit u = kt; LDS slot u*512 so fragment reads are
    // Bs[kt*512 + lane*8] (b128, conflict-free -- same addressing as R8).
    auto stage1 = [&](int buf, const u16* yb, int iu) {
        const int u = w * 2 + iu;
        load16(yb + u * 512 + lane * 8, &Bs[buf][u * 512]);
    };

    short8 a[2][16];
    auto loadA = [&](int kt) {
        #pragma unroll
        for (int rg = 0; rg < 2; ++rg)
            a[rg][kt] = *(const short8*)(
                Xs + ((size_t)(p32A + rg) * 16 + kt) * 512 + lane * 8);
    };

    floatx16 mnv[2], mxv[2];
    #pragma unroll
    for (int rg = 0; rg < 2; ++rg)
        #pragma unroll
        for (int r = 0; r < 16; ++r) {
            mnv[rg][r] = 3.4e38f;
            mxv[rg][r] = -3.4e38f;
        }

    floatx16 acc[2];
    const floatx16 FZ16 = (floatx16)(0.0f);

    auto fold = [&]() {
        #pragma unroll
        for (int rg = 0; rg < 2; ++rg)
            #pragma unroll
            for (int r = 0; r < 16; ++r) {
                float m = acc[rg][r];
                mnv[rg][r] = fminf(mnv[rg][r], m);
                mxv[rg][r] = fmaxf(mxv[rg][r], m);
            }
    };

    // 16 kt phases: {issue read kt+3 -> 2 MFMAs on bf[kt&3]}. 4-slot ring,
    // all indices compile-time after full unroll. dofold folds prev ct's
    // acc inside the first reads' latency window.
    auto compute = [&](int buf, int dofold) {
        const u16* bsb = &Bs[buf][0];
        auto rdB = [&](int kt) {
            return *(const short8*)(bsb + kt * 512 + lane * 8);
        };
        short8 bf[4];
        bf[0] = rdB(0); bf[1] = rdB(1); bf[2] = rdB(2);
        if (dofold) fold();
        #pragma unroll
        for (int kt = 0; kt < 16; ++kt) {
            if (kt + 3 < 16) bf[(kt + 3) & 3] = rdB(kt + 3);
            if (kt == 0) {
                acc[0] = __builtin_amdgcn_mfma_f32_32x32x16_bf16(
                    a[0][0], bf[0], FZ16, 0, 0, 0);
                acc[1] = __builtin_amdgcn_mfma_f32_32x32x16_bf16(
                    a[1][0], bf[0], FZ16, 0, 0, 0);
            } else {
                acc[0] = __builtin_amdgcn_mfma_f32_32x32x16_bf16(
                    a[0][kt], bf[kt & 3], acc[0], 0, 0, 0);
                acc[1] = __builtin_amdgcn_mfma_f32_32x32x16_bf16(
                    a[1][kt], bf[kt & 3], acc[1], 0, 0, 0);
            }
        }
    };

    // --- ct = 0, peeled: overlap A prologue with B0 DMA ---
    stage1(0, ybase, 0); stage1(0, ybase, 1);
    loadA(0); loadA(1); loadA(2); loadA(3);
    __syncthreads();         // drains B0 DMA (+ the early A loads)
    stage1(1, ybase + 8192, 0); stage1(1, ybase + 8192, 1);  // prefetch ct=1
    loadA(4); loadA(5); loadA(6); loadA(7);
    loadA(8); loadA(9); loadA(10); loadA(11);
    loadA(12); loadA(13); loadA(14); loadA(15);
    compute(0, 0);
    ybase += 8192;

    // --- cts 1..15: steady state; fold of ct-1 happens inside compute ---
    #pragma unroll 1
    for (int ct = 1; ct < 16; ++ct) {
        const int buf = ct & 1;
        __syncthreads();           // drains this ct's B DMA (issued a ct ago)
        if (ct < 15)
            stage1(buf ^ 1, ybase + 8192, 0), stage1(buf ^ 1, ybase + 8192, 1);
        compute(buf, 1);
        ybase += 8192;  // loop-carried: blocks cross-ct hoisting
    }
    fold();  // final ct's acc

    // Epilogue: 5-step butterfly over lane&31 (cols), eval C twice
    // (quasiconcavity), fire-and-forget atomicMin. Writers: lanes 0 and 32.
    // row = rowStart + w*64 + rg*32 + (r&3) + 8*(r>>2) + 4*(lane>>5).
    #pragma unroll
    for (int rg = 0; rg < 2; ++rg) {
        #pragma unroll
        for (int r = 0; r < 16; ++r) {
            float mn = mnv[rg][r];
            float mx = mxv[rg][r];
            #pragma unroll
            for (int mofs = 1; mofs < 32; mofs <<= 1) {
                mn = fminf(mn, __shfl_xor(mn, mofs, 64));
                mx = fmaxf(mx, __shfl_xor(mx, mofs, 64));
            }
            if ((lane & 31) == 0) {
                float cmin = fminf(c_of_m(mn), c_of_m(mx));
                int row = rowStart + w * 64 + rg * 32 +
                          (r & 3) + 8 * (r >> 2) + 4 * (lane >> 5);
                atomicMinFloat(&out[row], cmin);
            }
        }
    }
}

extern "C" void kernel_launch(void* const* d_in, const int* in_sizes, int n_in,
                              void* d_out, int out_size, void* d_ws, size_t ws_size,
                              hipStream_t stream) {
    const float* Ex = (const float*)d_in[0];
    const float* Ey = (const float*)d_in[1];
    float* out = (float*)d_out;
    u16* Xs = (u16*)d_ws;                // 4 MB, 32-row panel layout
    u16* Ys = Xs + (size_t)NROWS * DIM;  // 4 MB, 32-row panel layout

    hipLaunchKernelGGL(normalize_kernel, dim3(NROWS / 4, 2), dim3(256), 0, stream,
                       Ex, Ey, Xs, Ys, out);
    hipLaunchKernelGGL(gemm_min_kernel, dim3(16 * 16), dim3(512), 0, stream,
                       Xs, Ys, out);
}

// Round 11
// 94.684 us; speedup vs baseline: 1.1227x; 1.1227x over previous
//
#include <hip/hip_runtime.h>
#include <hip/hip_bf16.h>

typedef unsigned short u16;
typedef __attribute__((ext_vector_type(8))) short short8;
typedef __attribute__((ext_vector_type(4))) float floatx4;

#define NROWS 8192
#define DIM 256

__device__ __forceinline__ void atomicMinFloat(float* addr, float val) {
    if (val >= 0.0f) {
        atomicMin((int*)addr, __float_as_int(val));
    } else {
        atomicMax((unsigned int*)addr, __float_as_uint(val));
    }
}

__device__ __forceinline__ u16 f32_to_bf16_rne(float x) {
    unsigned int u = __float_as_uint(x);
    unsigned int r = (u + 0x7fffu + ((u >> 16) & 1u)) >> 16;
    return (u16)r;
}

// C(M) = -logp * exp(logp); quasiconcave in M => rowmin = min(C(minM), C(maxM)).
__device__ __forceinline__ float c_of_m(float m) {
    const float INV_SIG = 1.0f / 0.3f;
    const float KC = 0.28503427f;  // -ln(0.3) - 0.5*ln(2*pi)
    float z = (m - 1.0f) * INV_SIG;
    float logp = fmaf(-0.5f * z, z, KC);
    return -logp * __expf(logp);
}

// 16B async DMA global -> LDS. LDS dest is wave-uniform base + lane*16.
__device__ __forceinline__ void load16(const u16* g, u16* l) {
    __builtin_amdgcn_global_load_lds(
        (__attribute__((address_space(1))) void*)g,
        (__attribute__((address_space(3))) void*)l, 16, 0, 0);
}

// Normalize rows (L2-norm clamped at 1e-8), wave per row, float4 loads.
// BOTH X and Y are written in MFMA fragment ("panel") layout:
//   element (row r, k) -> flat[ ((p*8+kt)*64 + lq*16 + lm)*8 + j ]
//   p=r>>4, lm=r&15, kt=k>>5, lq=(k>>3)&3, j=k&7.
// A fragment load is then base + lane*16B: one coalesced dwordx4.
// Verified end-to-end R5/R11/R14/R15 (absmax 1.5e-5).
__global__ __launch_bounds__(256) void normalize_kernel(const float* __restrict__ Ex,
                                                        const float* __restrict__ Ey,
                                                        u16* __restrict__ Xs,
                                                        u16* __restrict__ Ys,
                                                        float* __restrict__ out) {
    const int t = threadIdx.x;
    const int ln = t & 63;
    const int row = blockIdx.x * 4 + (t >> 6);
    const float* src = (blockIdx.y == 0) ? Ex : Ey;
    u16* dst = (blockIdx.y == 0) ? Xs : Ys;

    float4 v = *(const float4*)(src + (size_t)row * DIM + ln * 4);
    float s = fmaf(v.x, v.x, fmaf(v.y, v.y, fmaf(v.z, v.z, v.w * v.w)));
    #pragma unroll
    for (int m = 32; m >= 1; m >>= 1) s += __shfl_xor(s, m, 64);
    float inv = 1.0f / fmaxf(sqrtf(s), 1e-8f);

    ushort4 o;
    o.x = f32_to_bf16_rne(v.x * inv);
    o.y = f32_to_bf16_rne(v.y * inv);
    o.z = f32_to_bf16_rne(v.z * inv);
    o.w = f32_to_bf16_rne(v.w * inv);

    const int p = row >> 4;
    const int lm = row & 15;
    const int kt = ln >> 3;
    const int lq = (ln >> 1) & 3;
    const int j4 = (ln & 1) * 4;
    const size_t off = ((size_t)((p * 8 + kt) * 64 + lq * 16 + lm)) * 8 + j4;
    *(ushort4*)(dst + off) = o;

    if (blockIdx.y == 0 && ln == 0) out[row] = __uint_as_float(0x7f800000u);  // +inf
}

// R27: R8 champion structure restored (16x16x32, 8 acc chains -- R10's
// 32x32 had only 2 dependent chains and regressed to 46 us). One change:
// B pipeline widened from 2 to 4 ring slots (cg-pairs), reads issued 3 kt
// ahead (up to ~6-8 outstanding ds_read_b128/wave, +16 VGPR). Basis (R7
// counter recalibration): MfmaUtil "49%" is gfx94x-formula-inflated; true
// walls per ct = MFMA 620 cyc/SIMD, LDS 1536 cyc/CU, measured 4300 ->
// nothing saturated = outstanding-op starvation. More reads in flight
// keeps the LDS pipe busy continuously. Early-fold (R8) retained; R9's
// rotation/waitcnt stay reverted.
// Grid 256 (1 block/CU); XCD swizzle keeps A+B in the local L2.
__global__ void __launch_bounds__(512, 2)
gemm_min_kernel(const u16* __restrict__ Xs,
                const u16* __restrict__ Ys,
                float* __restrict__ out) {
    __shared__ u16 Bs[2][16 * 512];  // 2 x 16 KB

    const int tid = threadIdx.x;
    const int w = tid >> 6;      // 0..7 row-group (64 rows each)
    const int lane = tid & 63;
    const int lq = lane >> 4;
    const int lm = lane & 15;

    // XCD-aware remap (dispatch i -> XCD i&7 round-robin): XCD x gets a
    // 4 row-tile x 8 col-group region. Bijective over the 16x16 grid.
    const int i = blockIdx.x;
    const int x = i & 7;
    const int jj = i >> 3;                      // 0..31 within XCD
    const int rt = (x & 3) * 4 + (jj & 3);      // row-tile 0..15
    const int cgrp = (x >> 2) * 8 + (jj >> 2);  // col-group 0..15

    const int rowStart = rt * 512;
    const int rowPan0 = rt * 32 + w * 4;
    const u16* ybase = Ys + (size_t)cgrp * 32 * 4096;  // advances 8192 u16/ct

    // Stage one 32col x 256k B tile (16 KB = 16 x 1 KB units) via DMA.
    // 8 waves x 2 units; unit u -> (col-panel u>>3, kt u&7); LDS slot u*512
    // so fragment reads are Bs[(cg*8+kt)*512 + lane*8] (b128, conflict-free).
    auto stage1 = [&](int buf, const u16* yb, int iu) {
        const int u = w * 2 + iu;
        load16(yb + (u >> 3) * 4096 + (u & 7) * 512 + lane * 8,
               &Bs[buf][u * 512]);
    };

    short8 a[4][8];
    auto loadA = [&](int kt) {
        #pragma unroll
        for (int rg = 0; rg < 4; ++rg)
            a[rg][kt] = *(const short8*)(
                Xs + ((size_t)(rowPan0 + rg) * 8 + kt) * 512 + lane * 8);
    };

    floatx4 mn4[4], mx4[4];
    #pragma unroll
    for (int rg = 0; rg < 4; ++rg) {
        mn4[rg] = (floatx4){3.4e38f, 3.4e38f, 3.4e38f, 3.4e38f};
        mx4[rg] = (floatx4){-3.4e38f, -3.4e38f, -3.4e38f, -3.4e38f};
    }

    floatx4 acc[4][2];
    const floatx4 FZ = (floatx4){0.0f, 0.0f, 0.0f, 0.0f};

    auto fold = [&]() {
        #pragma unroll
        for (int rg = 0; rg < 4; ++rg)
            #pragma unroll
            for (int cg = 0; cg < 2; ++cg)
                #pragma unroll
                for (int r = 0; r < 4; ++r) {
                    float m = acc[rg][cg][r];
                    mn4[rg][r] = fminf(mn4[rg][r], m);
                    mx4[rg][r] = fmaxf(mx4[rg][r], m);
                }
    };

    // 4-slot ring pipeline: slot s holds the cg-pair for kt with kt&3 == s.
    // Prologue fills kt=0..2; each kt's MFMA cluster is preceded by the
    // issue of kt+3's reads -- up to ~6-8 b128 in flight per wave.
    // dofold folds the previous ct's acc inside the prologue read window.
    auto compute = [&](int buf, int dofold) {
        const u16* bsb = &Bs[buf][0];
        short8 bf[4][2];
        auto rdB = [&](int slot, int kt) {
            bf[slot][0] = *(const short8*)(bsb + (0 * 8 + kt) * 512 + lane * 8);
            bf[slot][1] = *(const short8*)(bsb + (8 + kt) * 512 + lane * 8);
        };
        rdB(0, 0); rdB(1, 1); rdB(2, 2);
        if (dofold) fold();
        #pragma unroll
        for (int kt = 0; kt < 8; ++kt) {
            if (kt + 3 < 8) rdB((kt + 3) & 3, kt + 3);
            if (kt == 0) {
                #pragma unroll
                for (int cg = 0; cg < 2; ++cg)
                    #pragma unroll
                    for (int rg = 0; rg < 4; ++rg)
                        acc[rg][cg] = __builtin_amdgcn_mfma_f32_16x16x32_bf16(
                            a[rg][0], bf[0][cg], FZ, 0, 0, 0);
            } else {
                #pragma unroll
                for (int cg = 0; cg < 2; ++cg)
                    #pragma unroll
                    for (int rg = 0; rg < 4; ++rg)
                        acc[rg][cg] = __builtin_amdgcn_mfma_f32_16x16x32_bf16(
                            a[rg][kt], bf[kt & 3][cg], acc[rg][cg], 0, 0, 0);
            }
        }
    };

    // --- ct = 0, peeled: overlap A prologue with B0 DMA ---
    stage1(0, ybase, 0); stage1(0, ybase, 1);
    loadA(0); loadA(1);
    __syncthreads();         // drains B0 DMA (+ the early A loads)
    stage1(1, ybase + 8192, 0); stage1(1, ybase + 8192, 1);  // prefetch ct=1
    loadA(2); loadA(3); loadA(4); loadA(5); loadA(6); loadA(7);
    compute(0, 0);
    ybase += 8192;

    // --- cts 1..15: steady state; fold of ct-1 happens inside compute ---
    #pragma unroll 1
    for (int ct = 1; ct < 16; ++ct) {
        const int buf = ct & 1;
        __syncthreads();           // drains this ct's B DMA (issued a ct ago)
        if (ct < 15)
            stage1(buf ^ 1, ybase + 8192, 0), stage1(buf ^ 1, ybase + 8192, 1);
        compute(buf, 1);
        ybase += 8192;  // loop-carried: blocks cross-ct hoisting
    }
    fold();  // final ct's acc

    // Single epilogue: quad-lane reduce, eval C twice (quasiconcavity),
    // fire-and-forget atomicMin (no read guard -- R3 post-mortem).
    #pragma unroll
    for (int rg = 0; rg < 4; ++rg) {
        #pragma unroll
        for (int r = 0; r < 4; ++r) {
            float mn = mn4[rg][r];
            float mx = mx4[rg][r];
            #pragma unroll
            for (int mofs = 1; mofs < 16; mofs <<= 1) {
                mn = fminf(mn, __shfl_xor(mn, mofs, 64));
                mx = fmaxf(mx, __shfl_xor(mx, mofs, 64));
            }
            if (lm == 0) {
                float cmin = fminf(c_of_m(mn), c_of_m(mx));
                int row = rowStart + w * 64 + rg * 16 + lq * 4 + r;
                atomicMinFloat(&out[row], cmin);
            }
        }
    }
}

extern "C" void kernel_launch(void* const* d_in, const int* in_sizes, int n_in,
                              void* d_out, int out_size, void* d_ws, size_t ws_size,
                              hipStream_t stream) {
    const float* Ex = (const float*)d_in[0];
    const float* Ey = (const float*)d_in[1];
    float* out = (float*)d_out;
    u16* Xs = (u16*)d_ws;                // 4 MB, panel layout
    u16* Ys = Xs + (size_t)NROWS * DIM;  // 4 MB, panel layout

    hipLaunchKernelGGL(normalize_kernel, dim3(NROWS / 4, 2), dim3(256), 0, stream,
                       Ex, Ey, Xs, Ys, out);
    hipLaunchKernelGGL(gemm_min_kernel, dim3(16 * 16), dim3(512), 0, stream,
                       Xs, Ys, out);
}